// Round 1
// baseline (117.571 us; speedup 1.0000x reference)
//
#include <hip/hip_runtime.h>

// DendralNeuron: out[b,d] = min( min_f(x[b,f]-Wmin[d,f]), min_f(Wmax[d,f]-x[b,f]) )
// VALU-bound "min-GEMM". BM=64 x BN=32 tile, BK=16 chunks of F=784 (49 exact).
// Thread tile 4x2 strided by 16; LDS stride 20 floats (16B-aligned, <=2-way banks).

constexpr int F_DIM = 784;
constexpr int BM = 64;
constexpr int BN = 32;
constexpr int BK = 16;
constexpr int LSTR = BK + 4;          // 20 floats: 16B-aligned rows, spreads banks
constexpr int NCHUNK = F_DIM / BK;    // 49, no tail

__global__ __launch_bounds__(256, 1)
void dendral_min_kernel(const float* __restrict__ x,
                        const float* __restrict__ wmin,
                        const float* __restrict__ wmax,
                        float* __restrict__ out, int D) {
  __shared__ float lx[BM * LSTR];     // x tile  [64][20]
  __shared__ float lwn[BN * LSTR];    // wmin    [32][20]
  __shared__ float lwx[BN * LSTR];    // wmax    [32][20]

  const int t  = threadIdx.x;
  const int tx = t & 15;              // d-group: cols tx, tx+16
  const int ty = t >> 4;              // b-group: rows ty, ty+16, ty+32, ty+48
  const int b0 = blockIdx.x * BM;
  const int d0 = blockIdx.y * BN;

  // Staging assignment: x tile 64x16 = 256 float4 (one per thread);
  // wmin+wmax tiles 2x32x16 = 256 float4 (one per thread, wave-uniform split).
  const int xr = t >> 2;              // 0..63
  const int xc = (t & 3) << 2;        // 0,4,8,12
  const int wt = t >> 7;              // 0 -> wmin (waves 0,1), 1 -> wmax (waves 2,3)
  const int wr = (t & 127) >> 2;      // 0..31
  const int wc = (t & 3) << 2;

  const float* xg = x + (size_t)(b0 + xr) * F_DIM + xc;
  const float* wg = (wt ? wmax : wmin) + (size_t)(d0 + wr) * F_DIM + wc;
  float* lds_x = lx + xr * LSTR + xc;
  float* lds_w = (wt ? lwx : lwn) + wr * LSTR + wc;

  // Prefetch chunk 0 into registers.
  float4 px = *(const float4*)xg;
  float4 pw = *(const float4*)wg;

  float l1[4][2], mx[4][2];
#pragma unroll
  for (int r = 0; r < 4; ++r)
#pragma unroll
    for (int c = 0; c < 2; ++c) {
      l1[r][c] = __builtin_inff();
      mx[r][c] = -__builtin_inff();
    }

  for (int kc = 0; kc < NCHUNK; ++kc) {
    *(float4*)lds_x = px;
    *(float4*)lds_w = pw;
    __syncthreads();
    if (kc + 1 < NCHUNK) {            // register prefetch of next chunk (latency
      px = *(const float4*)(xg + (kc + 1) * BK);   // hidden behind compute below)
      pw = *(const float4*)(wg + (kc + 1) * BK);
    }
#pragma unroll
    for (int f = 0; f < BK; f += 4) {
      float4 xv[4], nv[2], wv[2];
#pragma unroll
      for (int r = 0; r < 4; ++r)
        xv[r] = *(const float4*)&lx[(ty + 16 * r) * LSTR + f];
#pragma unroll
      for (int c = 0; c < 2; ++c) {
        nv[c] = *(const float4*)&lwn[(tx + 16 * c) * LSTR + f];
        wv[c] = *(const float4*)&lwx[(tx + 16 * c) * LSTR + f];
      }
#pragma unroll
      for (int r = 0; r < 4; ++r)
#pragma unroll
        for (int c = 0; c < 2; ++c) {
          // L1 path: min over f of (x - wmin)  -> v_min3 pairs
          float a0 = xv[r].x - nv[c].x, a1 = xv[r].y - nv[c].y;
          float a2 = xv[r].z - nv[c].z, a3 = xv[r].w - nv[c].w;
          l1[r][c] = fminf(l1[r][c], fminf(a0, a1));
          l1[r][c] = fminf(l1[r][c], fminf(a2, a3));
          // L2 path: min_f(wmax - x) == -max_f(x - wmax) -> v_max3 pairs
          float u0 = xv[r].x - wv[c].x, u1 = xv[r].y - wv[c].y;
          float u2 = xv[r].z - wv[c].z, u3 = xv[r].w - wv[c].w;
          mx[r][c] = fmaxf(mx[r][c], fmaxf(u0, u1));
          mx[r][c] = fmaxf(mx[r][c], fmaxf(u2, u3));
        }
    }
    __syncthreads();
  }

#pragma unroll
  for (int r = 0; r < 4; ++r)
#pragma unroll
    for (int c = 0; c < 2; ++c) {
      const int b = b0 + ty + 16 * r;
      const int d = d0 + tx + 16 * c;
      out[(size_t)b * D + d] = fminf(l1[r][c], -mx[r][c]);
    }
}

extern "C" void kernel_launch(void* const* d_in, const int* in_sizes, int n_in,
                              void* d_out, int out_size, void* d_ws, size_t ws_size,
                              hipStream_t stream) {
  const float* x    = (const float*)d_in[0];
  const float* wmin = (const float*)d_in[1];
  const float* wmax = (const float*)d_in[2];
  float* out = (float*)d_out;
  const int B = in_sizes[0] / F_DIM;  // 1024
  const int D = in_sizes[1] / F_DIM;  // 512
  dim3 grid(B / BM, D / BN);          // 16 x 16 = 256 blocks -> 1 per CU
  dendral_min_kernel<<<grid, 256, 0, stream>>>(x, wmin, wmax, out, D);
  (void)n_in; (void)out_size; (void)d_ws; (void)ws_size;
}

// Round 2
// 94.637 us; speedup vs baseline: 1.2423x; 1.2423x over previous
//
#include <hip/hip_runtime.h>

// DendralNeuron: out[b,d] = min( min_f(x[b,f]-Wmin[d,f]), min_f(Wmax[d,f]-x[b,f]) )
// VALU-bound "min-GEMM". BM=64 x BN=32 tile, BK=16 chunks of F=784 (49 exact).
// F-reduction split 4-ways across gridDim.z -> 1024 blocks = 4 blocks/CU =
// 16 waves/CU (R1 showed 1 block/CU -> VALUBusy 53%, Occupancy 10%).
// Partials combined via float atomicMin trick against +inf-initialized out.

constexpr int F_DIM = 784;
constexpr int BM = 64;
constexpr int BN = 32;
constexpr int BK = 16;
constexpr int LSTR = BK + 4;          // 20 floats: 16B-aligned rows, spreads banks
constexpr int NCHUNK = F_DIM / BK;    // 49, no tail
constexpr int ZSPLIT = 4;             // F-split factor

__global__ __launch_bounds__(256, 4)
void dendral_init_kernel(float* __restrict__ out) {
  // out_size = 1024*512 = 524288 floats = 131072 float4 = 512 blocks x 256 thr
  const int i = blockIdx.x * 256 + threadIdx.x;
  const float inf = __builtin_inff();
  float4 v = {inf, inf, inf, inf};
  ((float4*)out)[i] = v;
}

__device__ inline void atomic_min_float(float* addr, float v) {
  if (v >= 0.0f) atomicMin((int*)addr, __float_as_int(v));
  else           atomicMax((unsigned int*)addr, __float_as_uint(v));
}

__global__ __launch_bounds__(256, 4)
void dendral_min_kernel(const float* __restrict__ x,
                        const float* __restrict__ wmin,
                        const float* __restrict__ wmax,
                        float* __restrict__ out, int D) {
  __shared__ float lx[BM * LSTR];     // x tile  [64][20]
  __shared__ float lwn[BN * LSTR];    // wmin    [32][20]
  __shared__ float lwx[BN * LSTR];    // wmax    [32][20]

  const int t  = threadIdx.x;
  const int tx = t & 15;              // d-group: cols tx, tx+16
  const int ty = t >> 4;              // b-group: rows ty, ty+16, ty+32, ty+48
  const int b0 = blockIdx.x * BM;
  const int d0 = blockIdx.y * BN;
  const int z  = blockIdx.z;
  const int c0 = (z * NCHUNK) / ZSPLIT;         // 0,12,24,36
  const int c1 = ((z + 1) * NCHUNK) / ZSPLIT;   // 12,24,36,49

  // Staging: x tile 64x16 = 256 float4 (one per thread);
  // wmin+wmax tiles 2x32x16 = 256 float4 (one per thread, wave-uniform split).
  const int xr = t >> 2;              // 0..63
  const int xc = (t & 3) << 2;        // 0,4,8,12
  const int wt = t >> 7;              // 0 -> wmin (waves 0,1), 1 -> wmax (2,3)
  const int wr = (t & 127) >> 2;      // 0..31
  const int wc = (t & 3) << 2;

  const float* xg = x + (size_t)(b0 + xr) * F_DIM + xc;
  const float* wg = (wt ? wmax : wmin) + (size_t)(d0 + wr) * F_DIM + wc;
  float* lds_x = lx + xr * LSTR + xc;
  float* lds_w = (wt ? lwx : lwn) + wr * LSTR + wc;

  // Prefetch first chunk of this z-slice into registers.
  float4 px = *(const float4*)(xg + c0 * BK);
  float4 pw = *(const float4*)(wg + c0 * BK);

  float l1[4][2], mx[4][2];
#pragma unroll
  for (int r = 0; r < 4; ++r)
#pragma unroll
    for (int c = 0; c < 2; ++c) {
      l1[r][c] = __builtin_inff();
      mx[r][c] = -__builtin_inff();
    }

  for (int kc = c0; kc < c1; ++kc) {
    *(float4*)lds_x = px;
    *(float4*)lds_w = pw;
    __syncthreads();
    if (kc + 1 < c1) {                // register prefetch of next chunk
      px = *(const float4*)(xg + (kc + 1) * BK);
      pw = *(const float4*)(wg + (kc + 1) * BK);
    }
#pragma unroll
    for (int f = 0; f < BK; f += 4) {
      float4 xv[4], nv[2], wv[2];
#pragma unroll
      for (int r = 0; r < 4; ++r)
        xv[r] = *(const float4*)&lx[(ty + 16 * r) * LSTR + f];
#pragma unroll
      for (int c = 0; c < 2; ++c) {
        nv[c] = *(const float4*)&lwn[(tx + 16 * c) * LSTR + f];
        wv[c] = *(const float4*)&lwx[(tx + 16 * c) * LSTR + f];
      }
#pragma unroll
      for (int r = 0; r < 4; ++r)
#pragma unroll
        for (int c = 0; c < 2; ++c) {
          // L1 path: min_f(x - wmin) -> v_min3 pairs
          float a0 = xv[r].x - nv[c].x, a1 = xv[r].y - nv[c].y;
          float a2 = xv[r].z - nv[c].z, a3 = xv[r].w - nv[c].w;
          l1[r][c] = fminf(l1[r][c], fminf(a0, a1));
          l1[r][c] = fminf(l1[r][c], fminf(a2, a3));
          // L2 path: min_f(wmax - x) == -max_f(x - wmax) -> v_max3 pairs
          float u0 = xv[r].x - wv[c].x, u1 = xv[r].y - wv[c].y;
          float u2 = xv[r].z - wv[c].z, u3 = xv[r].w - wv[c].w;
          mx[r][c] = fmaxf(mx[r][c], fmaxf(u0, u1));
          mx[r][c] = fmaxf(mx[r][c], fmaxf(u2, u3));
        }
    }
    __syncthreads();
  }

  // Combine this z-slice's partial into out via device-scope atomic min.
#pragma unroll
  for (int r = 0; r < 4; ++r)
#pragma unroll
    for (int c = 0; c < 2; ++c) {
      const int b = b0 + ty + 16 * r;
      const int d = d0 + tx + 16 * c;
      atomic_min_float(&out[(size_t)b * D + d], fminf(l1[r][c], -mx[r][c]));
    }
}

extern "C" void kernel_launch(void* const* d_in, const int* in_sizes, int n_in,
                              void* d_out, int out_size, void* d_ws, size_t ws_size,
                              hipStream_t stream) {
  const float* x    = (const float*)d_in[0];
  const float* wmin = (const float*)d_in[1];
  const float* wmax = (const float*)d_in[2];
  float* out = (float*)d_out;
  const int B = in_sizes[0] / F_DIM;  // 1024
  const int D = in_sizes[1] / F_DIM;  // 512

  dendral_init_kernel<<<out_size / (256 * 4), 256, 0, stream>>>(out);

  dim3 grid(B / BM, D / BN, ZSPLIT);  // 16 x 16 x 4 = 1024 blocks -> 4 per CU
  dendral_min_kernel<<<grid, 256, 0, stream>>>(x, wmin, wmax, out, D);
  (void)n_in; (void)d_ws; (void)ws_size;
}

// Round 3
// 93.241 us; speedup vs baseline: 1.2609x; 1.0150x over previous
//
#include <hip/hip_runtime.h>

// DendralNeuron: out[b,d] = min( min_f(x[b,f]-Wmin[d,f]), min_f(Wmax[d,f]-x[b,f]) )
// VALU-bound "min-GEMM". BM=64 x BN=32 tile, BK=16 chunks of F=784.
// R3: (a) packed-fp32 subtracts via v2f32 ext-vector (v_pk_add_f32 neg on
// gfx950) -> per-(b,d,f) VALU ops 3 -> 2; (b) ZSPLIT 4->7 (49=7x7 chunks)
// -> 1792 blocks = 7 blocks/CU = 28 waves/CU to cover barrier/LDS stalls.
// Partials combined via float atomicMin trick against +inf-initialized out.

constexpr int F_DIM = 784;
constexpr int BM = 64;
constexpr int BN = 32;
constexpr int BK = 16;
constexpr int LSTR = BK + 4;          // 20 floats: 16B-aligned rows, spreads banks
constexpr int NCHUNK = F_DIM / BK;    // 49
constexpr int ZSPLIT = 7;             // F-split factor; 7 chunks per z-slice

typedef float f4v __attribute__((ext_vector_type(4)));
typedef float f2v __attribute__((ext_vector_type(2)));

__global__ __launch_bounds__(256, 4)
void dendral_init_kernel(float* __restrict__ out) {
  const int i = blockIdx.x * 256 + threadIdx.x;
  const float inf = __builtin_inff();
  f4v v = {inf, inf, inf, inf};
  ((f4v*)out)[i] = v;
}

__device__ inline void atomic_min_float(float* addr, float v) {
  if (v >= 0.0f) atomicMin((int*)addr, __float_as_int(v));
  else           atomicMax((unsigned int*)addr, __float_as_uint(v));
}

__global__ __launch_bounds__(256, 4)
void dendral_min_kernel(const float* __restrict__ x,
                        const float* __restrict__ wmin,
                        const float* __restrict__ wmax,
                        float* __restrict__ out, int D) {
  __shared__ float lx[BM * LSTR];     // x tile  [64][20]
  __shared__ float lwn[BN * LSTR];    // wmin    [32][20]
  __shared__ float lwx[BN * LSTR];    // wmax    [32][20]

  const int t  = threadIdx.x;
  const int tx = t & 15;              // d-group: cols tx, tx+16
  const int ty = t >> 4;              // b-group: rows ty, ty+16, ty+32, ty+48
  const int b0 = blockIdx.x * BM;
  const int d0 = blockIdx.y * BN;
  const int c0 = blockIdx.z * (NCHUNK / ZSPLIT);   // 7 chunks per slice
  const int c1 = c0 + (NCHUNK / ZSPLIT);

  // Staging: x tile 64x16 = 256 float4 (one per thread);
  // wmin+wmax tiles 2x32x16 = 256 float4 (one per thread, wave-uniform split).
  const int xr = t >> 2;              // 0..63
  const int xc = (t & 3) << 2;        // 0,4,8,12
  const int wt = t >> 7;              // 0 -> wmin (waves 0,1), 1 -> wmax (2,3)
  const int wr = (t & 127) >> 2;      // 0..31
  const int wc = (t & 3) << 2;

  const float* xg = x + (size_t)(b0 + xr) * F_DIM + xc;
  const float* wg = (wt ? wmax : wmin) + (size_t)(d0 + wr) * F_DIM + wc;
  float* lds_x = lx + xr * LSTR + xc;
  float* lds_w = (wt ? lwx : lwn) + wr * LSTR + wc;

  // Prefetch first chunk of this z-slice into registers.
  f4v px = *(const f4v*)(xg + c0 * BK);
  f4v pw = *(const f4v*)(wg + c0 * BK);

  float l1[4][2], mx[4][2];
#pragma unroll
  for (int r = 0; r < 4; ++r)
#pragma unroll
    for (int c = 0; c < 2; ++c) {
      l1[r][c] = __builtin_inff();
      mx[r][c] = -__builtin_inff();
    }

  for (int kc = c0; kc < c1; ++kc) {
    *(f4v*)lds_x = px;
    *(f4v*)lds_w = pw;
    __syncthreads();
    if (kc + 1 < c1) {                // register prefetch of next chunk
      px = *(const f4v*)(xg + (kc + 1) * BK);
      pw = *(const f4v*)(wg + (kc + 1) * BK);
    }
#pragma unroll
    for (int f = 0; f < BK; f += 4) {
      f4v xv[4], nv[2], wv[2];
#pragma unroll
      for (int r = 0; r < 4; ++r)
        xv[r] = *(const f4v*)&lx[(ty + 16 * r) * LSTR + f];
#pragma unroll
      for (int c = 0; c < 2; ++c) {
        nv[c] = *(const f4v*)&lwn[(tx + 16 * c) * LSTR + f];
        wv[c] = *(const f4v*)&lwx[(tx + 16 * c) * LSTR + f];
      }
#pragma unroll
      for (int r = 0; r < 4; ++r)
#pragma unroll
        for (int c = 0; c < 2; ++c) {
          // L1 path: min_f(x - wmin); subs as v2f32 -> v_pk_add_f32 (neg)
          f2v a_lo = xv[r].xy - nv[c].xy;
          f2v a_hi = xv[r].zw - nv[c].zw;
          l1[r][c] = fminf(l1[r][c], fminf(a_lo.x, a_lo.y));  // v_min3
          l1[r][c] = fminf(l1[r][c], fminf(a_hi.x, a_hi.y));
          // L2 path: min_f(wmax - x) == -max_f(x - wmax)
          f2v u_lo = xv[r].xy - wv[c].xy;
          f2v u_hi = xv[r].zw - wv[c].zw;
          mx[r][c] = fmaxf(mx[r][c], fmaxf(u_lo.x, u_lo.y));  // v_max3
          mx[r][c] = fmaxf(mx[r][c], fmaxf(u_hi.x, u_hi.y));
        }
    }
    __syncthreads();
  }

  // Combine this z-slice's partial into out via device-scope atomic min.
#pragma unroll
  for (int r = 0; r < 4; ++r)
#pragma unroll
    for (int c = 0; c < 2; ++c) {
      const int b = b0 + ty + 16 * r;
      const int d = d0 + tx + 16 * c;
      atomic_min_float(&out[(size_t)b * D + d], fminf(l1[r][c], -mx[r][c]));
    }
}

extern "C" void kernel_launch(void* const* d_in, const int* in_sizes, int n_in,
                              void* d_out, int out_size, void* d_ws, size_t ws_size,
                              hipStream_t stream) {
  const float* x    = (const float*)d_in[0];
  const float* wmin = (const float*)d_in[1];
  const float* wmax = (const float*)d_in[2];
  float* out = (float*)d_out;
  const int B = in_sizes[0] / F_DIM;  // 1024
  const int D = in_sizes[1] / F_DIM;  // 512

  dendral_init_kernel<<<out_size / (256 * 4), 256, 0, stream>>>(out);

  dim3 grid(B / BM, D / BN, ZSPLIT);  // 16 x 16 x 7 = 1792 blocks -> 7 per CU
  dendral_min_kernel<<<grid, 256, 0, stream>>>(x, wmin, wmax, out, D);
  (void)n_in; (void)d_ws; (void)ws_size;
}